// Round 7
// baseline (704.492 us; speedup 1.0000x reference)
//
#include <hip/hip_runtime.h>
#include <stdint.h>

#define B_ROWS 4096
#define N_FEAT 32768
#define K_DIM  1024
#define BM 256
#define BN 256
#define NT2 (N_FEAT / BN)   // 128 n-tiles

typedef __attribute__((ext_vector_type(8))) short bf16x8;
typedef __attribute__((ext_vector_type(16))) float f32x16;
typedef __attribute__((address_space(1))) unsigned char ga_u8;
typedef __attribute__((address_space(3))) unsigned char lds_u8;

__device__ inline unsigned short f2bf(float f) {
  union { float f; unsigned u; } v; v.f = f;
  unsigned r = v.u + 0x7FFF + ((v.u >> 16) & 1);
  return (unsigned short)(r >> 16);
}
__device__ inline float bf2f(unsigned short u) {
  union { unsigned u; float f; } v; v.u = ((unsigned)u) << 16;
  return v.f;
}

// ---------------- K0: fused {normalize+cast inputs} and {cast features} ----------
__global__ void k_prep(const float* __restrict__ in, unsigned short* __restrict__ xbf,
                       const float* __restrict__ f, unsigned short* __restrict__ fbf) {
  int bid = blockIdx.x;
  int t = threadIdx.x;
  if (bid < B_ROWS) {
    int row = bid;
    float4 v = reinterpret_cast<const float4*>(in + (size_t)row * K_DIM)[t];
    float ssq = v.x * v.x + v.y * v.y + v.z * v.z + v.w * v.w;
    #pragma unroll
    for (int d = 1; d < 64; d <<= 1) ssq += __shfl_xor(ssq, d);
    __shared__ float sm[4];
    if ((t & 63) == 0) sm[t >> 6] = ssq;
    __syncthreads();
    float nrm = sqrtf(sm[0] + sm[1] + sm[2] + sm[3]);
    float inv = 1.0f / fmaxf(nrm, 1e-12f);
    ushort4 o;
    o.x = f2bf(v.x * inv); o.y = f2bf(v.y * inv);
    o.z = f2bf(v.z * inv); o.w = f2bf(v.w * inv);
    reinterpret_cast<ushort4*>(xbf + (size_t)row * K_DIM)[t] = o;
  } else {
    const long n4 = (long)N_FEAT * K_DIM / 4;
    long i = (long)(bid - B_ROWS) * 256 + t;
    const long stride = 8192L * 256;
    for (; i < n4; i += stride) {
      float4 v = reinterpret_cast<const float4*>(f)[i];
      ushort4 o;
      o.x = f2bf(v.x); o.y = f2bf(v.y); o.z = f2bf(v.z); o.w = f2bf(v.w);
      reinterpret_cast<ushort4*>(fbf)[i] = o;
    }
  }
}

// ---------------- K3: 256x256 8-wave 32x32x16-MFMA frag-major GEMM + logsumexp ----
// 32 phases (one K=32 half-tile each), 5 LDS slots x 32KB, stage depth 4,
// register double-buffered fragments (R6 schedule skeleton, absmax-0 verified).
// FRAG-MAJOR LDS: each 1KB line = one 32x32x16 fragment, lane-linear
// (lane l owns bytes [l*16, l*16+16) of its line) -> matches global_load_lds
// write law exactly; ds_read_b128 = all lanes consecutive 16B = conflict-free
// by construction, addressed as one per-lane base + immediate offsets.
// Slot layout: A lines 0..15 @ line*1024 (line = mf*2+ks, mf=0..7 rows mf*32..),
//              B lines 0..15 @ 16384 + line*1024 (line = nf*2+ks).

#define XSTR(s) STR(s)
#define STR(s) #s
#define WAITVN(N) asm volatile("s_waitcnt vmcnt(" XSTR(N) ")" ::: "memory")
#define LGKMN(N)  do { asm volatile("s_waitcnt lgkmcnt(" XSTR(N) ")" ::: "memory"); __builtin_amdgcn_sched_barrier(0); } while(0)
#define BAR       __builtin_amdgcn_s_barrier()
#define SCHED0    __builtin_amdgcn_sched_barrier(0)
#define PRIO1     __builtin_amdgcn_s_setprio(1)
#define PRIO0     __builtin_amdgcn_s_setprio(0)

__launch_bounds__(512, 2)
__global__ void k_gemm8(const unsigned short* __restrict__ xbf,
                        const unsigned short* __restrict__ fbf,
                        float* __restrict__ m_part, float* __restrict__ l_part) {
  __shared__ __align__(16) char lds_all[163840];   // 5 slots x 32KB
  char* ldsc = lds_all;

  int tid = threadIdx.x;
  int lane = tid & 63;
  int wid = tid >> 6;          // 0..7
  int wr = wid >> 2;           // 0..1  (m half: rows wr*128..)
  int wc = wid & 3;            // 0..3  (n quarter: cols wc*64..)

  // XCD-aware bijective swizzle (2048 blocks % 8 == 0)
  int bid = blockIdx.x;
  int swz = (bid & 7) * 256 + (bid >> 3);
  int mt = swz >> 7;           // 0..15
  int nt = swz & 127;          // 0..127
  int mBase = mt * BM, nBase = nt * BN;

  // staging source bases: wave wid stages A-frag rows wid*32.., B-frag cols wid*32..
  // lane l supplies elems k = (l>>5)*8 .. +8 of row (base + (l&31)).
  const char* srcA = (const char*)xbf + (size_t)(mBase + wid * 32 + (lane & 31)) * (K_DIM * 2)
                     + ((lane >> 5) * 16);
  const char* srcB = (const char*)fbf + (size_t)(nBase + wid * 32 + (lane & 31)) * (K_DIM * 2)
                     + ((lane >> 5) * 16);

  // fragment-read per-lane bases
  char* aBase = ldsc + lane * 16 + wr * 8192;            // + slot*32768 + (mf*2+ks)*1024
  char* bBase = ldsc + lane * 16 + 16384 + wc * 4096;    // + slot*32768 + (nf*2+ks)*1024

#define STAGE5(SLOT, H) do { \
    const char* gA = srcA + (H) * 64; \
    char* dA = ldsc + (SLOT) * 32768 + wid * 2048; \
    __builtin_amdgcn_global_load_lds((const ga_u8*)gA, (lds_u8*)dA, 16, 0, 0); \
    __builtin_amdgcn_global_load_lds((const ga_u8*)(gA + 32), (lds_u8*)(dA + 1024), 16, 0, 0); \
    const char* gB = srcB + (H) * 64; \
    char* dB = ldsc + (SLOT) * 32768 + 16384 + wid * 2048; \
    __builtin_amdgcn_global_load_lds((const ga_u8*)gB, (lds_u8*)dB, 16, 0, 0); \
    __builtin_amdgcn_global_load_lds((const ga_u8*)(gB + 32), (lds_u8*)(dB + 1024), 16, 0, 0); \
  } while(0)

#define LDF(AA, BB, SLOT) do { \
    char* sa = aBase + (SLOT) * 32768; \
    _Pragma("unroll") \
    for (int mf = 0; mf < 4; ++mf) \
      _Pragma("unroll") \
      for (int ks = 0; ks < 2; ++ks) \
        AA[mf][ks] = *reinterpret_cast<const bf16x8*>(sa + (mf * 2 + ks) * 1024); \
    char* sb = bBase + (SLOT) * 32768; \
    _Pragma("unroll") \
    for (int nf = 0; nf < 2; ++nf) \
      _Pragma("unroll") \
      for (int ks = 0; ks < 2; ++ks) \
        BB[nf][ks] = *reinterpret_cast<const bf16x8*>(sb + (nf * 2 + ks) * 1024); \
  } while(0)

#define MM5(AA, BB) do { \
    _Pragma("unroll") \
    for (int ks = 0; ks < 2; ++ks) \
      _Pragma("unroll") \
      for (int mf = 0; mf < 4; ++mf) \
        _Pragma("unroll") \
        for (int nf = 0; nf < 2; ++nf) \
          acc[mf][nf] = __builtin_amdgcn_mfma_f32_32x32x16_bf16(AA[mf][ks], BB[nf][ks], acc[mf][nf], 0, 0, 0); \
  } while(0)

#define PHASE5(SNXT, SSTG, DOST, DOLD, VM, LG, ACUR, BCUR, ANXT, BNXT, H) do { \
    if (DOST) { STAGE5(SSTG, H); } \
    WAITVN(VM); \
    if (DOLD) { LDF(ANXT, BNXT, SNXT); } \
    LGKMN(LG); \
    PRIO1; MM5(ACUR, BCUR); PRIO0; \
    BAR; SCHED0; \
  } while(0)

#define PH_E(SNXT, SSTG, H) PHASE5(SNXT, SSTG, 1, 1, 8, 12, a0, b0, a1, b1, H)
#define PH_O(SNXT, SSTG, H) PHASE5(SNXT, SSTG, 1, 1, 8, 12, a1, b1, a0, b0, H)

  f32x16 acc[4][2];
  #pragma unroll
  for (int i = 0; i < 4; ++i)
    #pragma unroll
    for (int j = 0; j < 2; ++j)
      #pragma unroll
      for (int r = 0; r < 16; ++r)
        acc[i][j][r] = 0.f;
  bf16x8 a0[4][2], b0[2][2], a1[4][2], b1[2][2];

  // Prologue: stage halves 0..3 into slots 0..3; retire 0,1; publish; preload frags(0).
  STAGE5(0, 0); STAGE5(1, 1); STAGE5(2, 2); STAGE5(3, 3);
  WAITVN(8);
  BAR; SCHED0;
  LDF(a0, b0, 0);     // 12 lgkm outstanding entering phase 0

  // P0..P27 (steady state)
  PH_E(1, 4, 4);   PH_O(2, 0, 5);   PH_E(3, 1, 6);   PH_O(4, 2, 7);   PH_E(0, 3, 8);
  PH_O(1, 4, 9);   PH_E(2, 0, 10);  PH_O(3, 1, 11);  PH_E(4, 2, 12);  PH_O(0, 3, 13);
  PH_E(1, 4, 14);  PH_O(2, 0, 15);  PH_E(3, 1, 16);  PH_O(4, 2, 17);  PH_E(0, 3, 18);
  PH_O(1, 4, 19);  PH_E(2, 0, 20);  PH_O(3, 1, 21);  PH_E(4, 2, 22);  PH_O(0, 3, 23);
  PH_E(1, 4, 24);  PH_O(2, 0, 25);  PH_E(3, 1, 26);  PH_O(4, 2, 27);  PH_E(0, 3, 28);
  PH_O(1, 4, 29);  PH_E(2, 0, 30);  PH_O(3, 1, 31);
  // Tail: P28..P31 (no staging; drain vmcnt 4->0)
  PHASE5(4, 0, 0, 1, 4, 12, a0, b0, a1, b1, 0);   // P28
  PHASE5(0, 0, 0, 1, 0, 12, a1, b1, a0, b0, 0);   // P29
  PHASE5(1, 0, 0, 1, 0, 12, a0, b0, a1, b1, 0);   // P30
  PHASE5(0, 0, 0, 0, 0, 0,  a1, b1, a0, b0, 0);   // P31

  // ---------------- fused epilogue: per-row max + sumexp over this block's 256 cols
  // C layout (32x32): col = lane&31 (+32*nf +64*wc), row = (reg&3)+8*(reg>>2)+4*(lane>>5)
  //                   (+32*mf +128*wr)
  asm volatile("s_waitcnt vmcnt(0) lgkmcnt(0)" ::: "memory");
  __syncthreads();
  float* sm_m = (float*)lds_all;            // [4][256]
  float* sm_l = (float*)(lds_all + 4096);

  #pragma unroll
  for (int mf = 0; mf < 4; ++mf)
    #pragma unroll
    for (int nf = 0; nf < 2; ++nf)
      acc[mf][nf] = acc[mf][nf] * 20.0f;    // 1/temp

  #pragma unroll
  for (int mf = 0; mf < 4; ++mf) {
    #pragma unroll
    for (int reg = 0; reg < 16; ++reg) {
      float mx = fmaxf(acc[mf][0][reg], acc[mf][1][reg]);
      mx = fmaxf(mx, __shfl_xor(mx, 1));
      mx = fmaxf(mx, __shfl_xor(mx, 2));
      mx = fmaxf(mx, __shfl_xor(mx, 4));
      mx = fmaxf(mx, __shfl_xor(mx, 8));
      mx = fmaxf(mx, __shfl_xor(mx, 16));
      float sum = __expf(acc[mf][0][reg] - mx) + __expf(acc[mf][1][reg] - mx);
      sum += __shfl_xor(sum, 1);
      sum += __shfl_xor(sum, 2);
      sum += __shfl_xor(sum, 4);
      sum += __shfl_xor(sum, 8);
      sum += __shfl_xor(sum, 16);
      if ((lane & 31) == 0) {
        int rl = (reg & 3) + 8 * (reg >> 2) + 4 * (lane >> 5);
        int r = wr * 128 + mf * 32 + rl;
        sm_m[wc * 256 + r] = mx;
        sm_l[wc * 256 + r] = sum;
      }
    }
  }
  __syncthreads();
  if (tid < 256) {
    float M = sm_m[tid], L = sm_l[tid];
    #pragma unroll
    for (int w = 1; w < 4; ++w) {
      float mo = sm_m[w * 256 + tid], lo = sm_l[w * 256 + tid];
      float mn = fmaxf(M, mo);
      L = L * __expf(M - mn) + lo * __expf(mo - mn);
      M = mn;
    }
    // transposed (coalesced) partials: [nt][row]
    size_t idx = (size_t)nt * B_ROWS + (mBase + tid);
    m_part[idx] = M;
    l_part[idx] = L;
  }
}

// ---------------- K4: combine 128 partials per row + target logit -> nll --------
__global__ void k_comb(const float* __restrict__ m_part, const float* __restrict__ l_part,
                       const unsigned short* __restrict__ xbf,
                       const unsigned short* __restrict__ fbf,
                       const int* __restrict__ tgt, float* __restrict__ nll) {
  int row = blockIdx.x;
  int lane = threadIdx.x;   // 64

  // target-column logit (bf16 dot, same data as GEMM for error cancellation)
  int t = tgt[row];
  const uint4* xa = reinterpret_cast<const uint4*>(xbf + (size_t)row * K_DIM + lane * 16);
  const uint4* fa = reinterpret_cast<const uint4*>(fbf + (size_t)t * K_DIM + lane * 16);
  float s = 0.f;
  #pragma unroll
  for (int j = 0; j < 2; ++j) {
    uint4 av = xa[j], fv = fa[j];
    const unsigned* ap = &av.x;
    const unsigned* fp = &fv.x;
    #pragma unroll
    for (int q = 0; q < 4; ++q) {
      s += bf2f((unsigned short)(ap[q] & 0xffff)) * bf2f((unsigned short)(fp[q] & 0xffff));
      s += bf2f((unsigned short)(ap[q] >> 16)) * bf2f((unsigned short)(fp[q] >> 16));
    }
  }
  #pragma unroll
  for (int d = 1; d < 64; d <<= 1) s += __shfl_xor(s, d);

  // logsumexp combine over 128 n-tiles ([nt][row] layout)
  float m = m_part[(size_t)lane * B_ROWS + row];
  float l = l_part[(size_t)lane * B_ROWS + row];
  float m2 = m_part[(size_t)(lane + 64) * B_ROWS + row];
  float l2 = l_part[(size_t)(lane + 64) * B_ROWS + row];
  float mn = fmaxf(m, m2);
  l = l * __expf(m - mn) + l2 * __expf(m2 - mn);
  m = mn;
  #pragma unroll
  for (int d = 1; d < 64; d <<= 1) {
    float mo = __shfl_xor(m, d);
    float lo = __shfl_xor(l, d);
    float mx = fmaxf(m, mo);
    l = l * __expf(m - mx) + lo * __expf(mo - mx);
    m = mx;
  }
  if (lane == 0) nll[row] = m + __logf(l) - s * 20.0f;
}

// ---------------- K5: mean over rows -> out[0] ----------------
__global__ void k_mean(const float* __restrict__ nll, float* __restrict__ out) {
  int t = threadIdx.x;   // 1024
  float s = 0.f;
  #pragma unroll
  for (int i = 0; i < 4; ++i) s += nll[t + i * 1024];
  #pragma unroll
  for (int d = 1; d < 64; d <<= 1) s += __shfl_xor(s, d);
  __shared__ float sm[16];
  if ((t & 63) == 0) sm[t >> 6] = s;
  __syncthreads();
  if (t == 0) {
    float tot = 0.f;
    #pragma unroll
    for (int w = 0; w < 16; ++w) tot += sm[w];
    out[0] = tot * (1.0f / B_ROWS);
  }
}

extern "C" void kernel_launch(void* const* d_in, const int* in_sizes, int n_in,
                              void* d_out, int out_size, void* d_ws, size_t ws_size,
                              hipStream_t stream) {
  const float* inputs = (const float*)d_in[0];
  // d_in[1] = targets (unused by the loss)
  const int* ctgt = (const int*)d_in[2];
  const float* feats = (const float*)d_in[3];
  float* out = (float*)d_out;

  char* ws = (char*)d_ws;
  unsigned short* xbf = (unsigned short*)ws;                          // 8 MB
  unsigned short* fbf = (unsigned short*)(ws + (8ull << 20));         // 64 MB
  float* m_part = (float*)(ws + (72ull << 20));                       // 2 MB
  float* l_part = (float*)(ws + (74ull << 20));                       // 2 MB
  float* nll = (float*)(ws + (76ull << 20));                          // 16 KB

  k_prep<<<B_ROWS + 8192, 256, 0, stream>>>(inputs, xbf, feats, fbf);
  k_gemm8<<<(B_ROWS / BM) * (N_FEAT / BN), 512, 0, stream>>>(xbf, fbf, m_part, l_part);
  k_comb<<<B_ROWS, 64, 0, stream>>>(m_part, l_part, xbf, fbf, ctgt, nll);
  k_mean<<<1, 1024, 0, stream>>>(nll, out);
}